// Round 6
// baseline (414.140 us; speedup 1.0000x reference)
//
#include <hip/hip_runtime.h>

// GraphFeaturesStackPad on MI355X.
// Stage 1: bf16 MFMA fused up/gate projection + sigmoid-gate + IN-REGISTER
//          segment-sum (atomicAdd into d_out as fp32 graph_sums accumulator).
// Stage 2: fp32 in-place GEMM graph_sums @ W_func + b_func.
// d_ws usage: ntiles ints (~31 KB) for per-tile first-graph index.
//
// R8 change vs R7 (post-mortem: spill fixed, stage1 ~111 us vs 39 us BW
// floor; per-tile wall ~17.5k cy vs ~4k cy of work -> stall-bound):
//  - LOOP SKELETON REORDERED. Old: stage(consume pf) was the FIRST phase,
//    and its vmcnt wait (forced to vmcnt(0) by the variable atomic count of
//    the divergent reduce loop) sat right after the previous iteration's
//    atomics -> exposed ~1-2k cy of atomic L2 latency per tile, plus the
//    prefetch had no compute cover before its wait.
//    New order: issue pf(i+1) -> issue window(i+1) -> MFMA+sigmoid(Xs[b])
//    -> stage(i+1 -> Xs[b^1]) -> reduce(i) atomics -> bar.
//    The stage's vmcnt(0) now sits AFTER the MFMA phase: atomics(i-1) are
//    a full phase stale (retired), and pf(i+1) gets ~1.5-2k cy of cover.
//    Still exactly ONE barrier per tile; Xs[b] reads vs Xs[b^1] writes are
//    disjoint, shfls drain at the barrier's lgkmcnt(0).
//  - keeps R7: (256,2) no-spill, grid 512, in-register reduce, clamped
//    unconditional VMEM, lane-resident pipelined starts window.
// Prediction: stage1 -> 85-100 us, total -> 375-388 us, VGPR 190-215.

typedef __bf16 bf16_t;
typedef bf16_t bf16x8 __attribute__((ext_vector_type(8)));
typedef float  f32x4  __attribute__((ext_vector_type(4)));

#define XS_STRIDE 144   // shorts; 288 B row = 72 dwords -> 4-way banks on b128

__device__ __forceinline__ unsigned short f2bf(float f) {
  unsigned int u = __float_as_uint(f);
  u += 0x7fffu + ((u >> 16) & 1u);   // RNE
  return (unsigned short)(u >> 16);
}

// LDS-only barrier: drains this wave's LDS ops then barriers; global loads
// (vmcnt) stay in flight, so the pipelined next-tile loads overlap compute.
__device__ __forceinline__ void bar_lds() {
  asm volatile("s_waitcnt lgkmcnt(0)\n\ts_barrier" ::: "memory");
}

__global__ void tile_seg_kernel(const int* __restrict__ starts,
                                int* __restrict__ tile_seg,
                                int ntiles, int G) {
  int i = blockIdx.x * blockDim.x + threadIdx.x;
  if (i >= ntiles) return;
  int n0 = i * 64;
  int lo = 0, hi = G - 1;            // largest g with starts[g] <= n0
  while (lo < hi) {
    int mid = (lo + hi + 1) >> 1;
    if (starts[mid] <= n0) lo = mid; else hi = mid - 1;
  }
  tile_seg[i] = lo;
}

__global__ __launch_bounds__(256, 2)
void stage1_kernel(const float* __restrict__ X,
                   const float* __restrict__ Wu, const float* __restrict__ bu,
                   const float* __restrict__ Wg, const float* __restrict__ bg,
                   const int* __restrict__ starts,
                   const int* __restrict__ tile_seg,
                   float* __restrict__ gsum, int V, int G, int ntiles)
{
  __shared__ unsigned short Xs[2][64 * XS_STRIDE]; // double-buffered bf16 tile (36.9 KB)

  const int tid  = threadIdx.x;
  const int lane = tid & 63;
  const int wave = tid >> 6;          // 4 waves; wave owns f-strip [wave*32, +32)
  const int quad = lane >> 4;
  const int l15  = lane & 15;

  // Persistent B fragments (W_up / W_gate) in registers, loaded once per block.
  // B-frag layout: lane holds B[k = s*32 + quad*8 + j][n = lane&15].
  bf16x8 Bu[2][4], Bg[2][4];
  float bup[2], bgt[2];
#pragma unroll
  for (int t = 0; t < 2; ++t) {
    const int f = wave * 32 + t * 16 + l15;
    bup[t] = bu[f];
    bgt[t] = bg[f];
#pragma unroll
    for (int s = 0; s < 4; ++s) {
      const int k0 = s * 32 + quad * 8;
      union { unsigned short us[8]; bf16x8 v; } a, b;
#pragma unroll
      for (int j = 0; j < 8; ++j) {
        a.us[j] = f2bf(Wu[(k0 + j) * 128 + f]);
        b.us[j] = f2bf(Wg[(k0 + j) * 128 + f]);
      }
      Bu[t][s] = a.v;
      Bg[t][s] = b.v;
    }
  }

  f32x4 ld[8];
  int tile = blockIdx.x;
  int g0v, sval;

  // ---- prologue: load + stage tile 0 into Xs[0], window(t0) ----
  {
    g0v  = tile_seg[tile];
    sval = starts[min(g0v + lane, G)];
    const int n0 = tile * 64;
#pragma unroll
    for (int i = 0; i < 8; ++i) {
      const int flat = tid + i * 256;
      const int n = min(n0 + (flat >> 5), V - 1);
      const int k = (flat & 31) << 2;
      ld[i] = *(const f32x4*)(X + (size_t)n * 128 + k);
    }
#pragma unroll
    for (int i = 0; i < 8; ++i) {
      const int flat = tid + i * 256;
      const int n = flat >> 5;
      const int k = (flat & 31) << 2;
      const unsigned int p0 =
          (unsigned int)f2bf(ld[i][0]) | ((unsigned int)f2bf(ld[i][1]) << 16);
      const unsigned int p1 =
          (unsigned int)f2bf(ld[i][2]) | ((unsigned int)f2bf(ld[i][3]) << 16);
      *(uint2*)&Xs[0][n * XS_STRIDE + k] = make_uint2(p0, p1);
    }
    bar_lds();
  }

  int it = 0;
  for (; tile < ntiles; tile += gridDim.x, ++it) {
    const int b     = it & 1;
    const int n0    = tile * 64;
    const int n_end = min(n0 + 64, V);
    const int g0 = g0v;     // this tile's window (pipelined last iteration)
    const int sv = sval;
    const unsigned short* xb = Xs[b];
    unsigned short*       xn = Xs[b ^ 1];

    // 1) issue next tile's global loads (clamped, unconditional); they get
    //    the whole window+MFMA phase of cover before the stage consumes them
    const int nextc = min(tile + (int)gridDim.x, ntiles - 1);
    {
      const int m0 = nextc * 64;
#pragma unroll
      for (int i = 0; i < 8; ++i) {
        const int flat = tid + i * 256;
        const int n = min(m0 + (flat >> 5), V - 1);
        const int k = (flat & 31) << 2;
        ld[i] = *(const f32x4*)(X + (size_t)n * 128 + k);
      }
    }
    // 2) issue next tile's starts window (dependent L2 pair; consumed next
    //    iteration's reduce -> a full iteration of cover)
    g0v  = tile_seg[nextc];
    sval = starts[min(g0v + lane, G)];

    // 3) MFMA phase + in-register sigmoid epilogue: gv[sub][t][r]
    float gv[4][2][4];
#pragma unroll
    for (int sub = 0; sub < 4; ++sub) {
      bf16x8 A[4];
      const int nl = sub * 16 + l15;   // A-frag: A[m=lane&15][k=quad*8+j]
#pragma unroll
      for (int s = 0; s < 4; ++s)
        A[s] = *(const bf16x8*)&xb[nl * XS_STRIDE + s * 32 + quad * 8];
#pragma unroll
      for (int t = 0; t < 2; ++t) {
        f32x4 au = {0.f, 0.f, 0.f, 0.f};
        f32x4 ag = {0.f, 0.f, 0.f, 0.f};
#pragma unroll
        for (int s = 0; s < 4; ++s) {
          au = __builtin_amdgcn_mfma_f32_16x16x32_bf16(A[s], Bu[t][s], au, 0, 0, 0);
          ag = __builtin_amdgcn_mfma_f32_16x16x32_bf16(A[s], Bg[t][s], ag, 0, 0, 0);
        }
        // D layout: col=lane&15 (feature), row=quad*4+r (node within sub-16)
#pragma unroll
        for (int r = 0; r < 4; ++r) {
          const float up = au[r] + bup[t];
          const float gt = ag[r] + bgt[t];
          gv[sub][t][r] = up * __builtin_amdgcn_rcpf(1.f + __expf(-gt));
        }
      }
    }

    // 4) stage next tile: consume ld[] (vmcnt wait lands AFTER the MFMA
    //    phase; previous reduce's atomics retired long ago, pf had cover)
#pragma unroll
    for (int i = 0; i < 8; ++i) {
      const int flat = tid + i * 256;
      const int n = flat >> 5;
      const int k = (flat & 31) << 2;
      const unsigned int p0 =
          (unsigned int)f2bf(ld[i][0]) | ((unsigned int)f2bf(ld[i][1]) << 16);
      const unsigned int p1 =
          (unsigned int)f2bf(ld[i][2]) | ((unsigned int)f2bf(ld[i][3]) << 16);
      *(uint2*)&xn[n * XS_STRIDE + k] = make_uint2(p0, p1);
    }

    // 5) in-register segment reduction -> atomics (LAST VMEM of the iter:
    //    they get next iteration's pf+window+MFMA to complete)
    {
      int i = 0;
      int sg = __shfl(sv, 0);
      while (sg < n_end && i < 63) {
        const int snext = __shfl(sv, i + 1);
        const int r0 = max(sg, n0) - n0;
        const int r1 = min(snext - 1, n_end) - n0;  // excludes graph's last node
        if (r1 > r0) {                               // wave-uniform branch
          float p0 = 0.f, p1 = 0.f;
#pragma unroll
          for (int sub = 0; sub < 4; ++sub) {
#pragma unroll
            for (int r = 0; r < 4; ++r) {
              const int row = sub * 16 + quad * 4 + r;
              const bool in = (row >= r0) && (row < r1);
              p0 += in ? gv[sub][0][r] : 0.f;
              p1 += in ? gv[sub][1][r] : 0.f;
            }
          }
          // butterfly across quads (lane^16, lane^32): all lanes get totals
          p0 += __shfl_xor(p0, 16); p0 += __shfl_xor(p0, 32);
          p1 += __shfl_xor(p1, 16); p1 += __shfl_xor(p1, 32);
          if (quad == 0)
            atomicAdd(&gsum[(size_t)(g0 + i) * 128 + wave * 32 + l15], p0);
          else if (quad == 1)
            atomicAdd(&gsum[(size_t)(g0 + i) * 128 + wave * 32 + 16 + l15], p1);
        }
        sg = snext;
        ++i;
      }
    }

    // 6) one barrier per tile: Xs[b^1] writes visible for next MFMA; this
    //    wave's shfls/ds ops drained by the lgkmcnt(0) inside bar_lds
    bar_lds();
  }
}

__global__ __launch_bounds__(256)
void stage2_kernel(const float* __restrict__ Wf, const float* __restrict__ bfv,
                   float* __restrict__ out, int G)
{
  __shared__ float Gsm[32 * 132];
  const int g0  = blockIdx.x * 32;
  const int tid = threadIdx.x;

  // stage this block's 32 graph_sums rows (then safe to overwrite in-place)
  for (int i = tid; i < 32 * 32; i += 256) {
    const int r = i >> 5;
    const int c = (i & 31) << 2;
    const int g = g0 + r;
    f32x4 v = {0.f, 0.f, 0.f, 0.f};
    if (g < G) v = *(const f32x4*)(out + (size_t)g * 128 + c);
    *(f32x4*)&Gsm[r * 132 + c] = v;
  }
  __syncthreads();

  const int fq  = tid & 31;
  const int f0  = fq << 2;            // 4 consecutive features
  const int grp = tid >> 5;           // 8 groups x 4 graphs
  float acc[4][4];
#pragma unroll
  for (int i = 0; i < 4; ++i)
#pragma unroll
    for (int j = 0; j < 4; ++j) acc[i][j] = 0.f;

#pragma unroll 4
  for (int k = 0; k < 128; ++k) {
    const f32x4 w = *(const f32x4*)(Wf + (size_t)k * 128 + f0);
#pragma unroll
    for (int i = 0; i < 4; ++i) {
      const float gv = Gsm[(grp * 4 + i) * 132 + k];
      acc[i][0] += gv * w[0];
      acc[i][1] += gv * w[1];
      acc[i][2] += gv * w[2];
      acc[i][3] += gv * w[3];
    }
  }

  const f32x4 bb = *(const f32x4*)(bfv + f0);
#pragma unroll
  for (int i = 0; i < 4; ++i) {
    const int g = g0 + grp * 4 + i;
    if (g < G) {
      f32x4 o = {acc[i][0] + bb[0], acc[i][1] + bb[1],
                 acc[i][2] + bb[2], acc[i][3] + bb[3]};
      *(f32x4*)(out + (size_t)g * 128 + f0) = o;
    }
  }
}

extern "C" void kernel_launch(void* const* d_in, const int* in_sizes, int n_in,
                              void* d_out, int out_size, void* d_ws, size_t ws_size,
                              hipStream_t stream)
{
  const float* X      = (const float*)d_in[0];
  const float* Wu     = (const float*)d_in[1];
  const float* bu     = (const float*)d_in[2];
  const float* Wg     = (const float*)d_in[3];
  const float* bg     = (const float*)d_in[4];
  const float* Wf     = (const float*)d_in[5];
  const float* bf_    = (const float*)d_in[6];
  const int*   starts = (const int*)d_in[7];

  const int G = in_sizes[7] - 1;
  const int V = in_sizes[0] / 128;
  const int ntiles = (V + 63) / 64;

  int*   tile_seg = (int*)d_ws;          // ntiles ints (~31 KB)
  float* gsum     = (float*)d_out;       // graph_sums accumulates in d_out

  hipMemsetAsync(d_out, 0, (size_t)G * 128 * sizeof(float), stream);
  tile_seg_kernel<<<(ntiles + 255) / 256, 256, 0, stream>>>(starts, tile_seg, ntiles, G);
  stage1_kernel<<<512, 256, 0, stream>>>(X, Wu, bu, Wg, bg, starts, tile_seg,
                                         gsum, V, G, ntiles);
  stage2_kernel<<<(G + 31) / 32, 256, 0, stream>>>(Wf, bf_, gsum, G);
}

// Round 7
// 403.332 us; speedup vs baseline: 1.0268x; 1.0268x over previous
//
#include <hip/hip_runtime.h>

// GraphFeaturesStackPad on MI355X.
// Stage 1: bf16 MFMA fused up/gate projection + sigmoid-gate + segment-sum
//          into a BLOCK-PRIVATE LDS accumulator (no atomics), flushed once
//          per block with plain stores (each block owns GPB graphs).
// Stage 2: fp32 in-place GEMM graph_sums @ W_func + b_func.
//
// R9 change vs R7/R8 (post-mortem: both stall theories traced to ONE root):
//  - The reduce's atomicAdds have a data-dependent count (divergent while
//    loop), so every stage-phase wait degenerates to vmcnt(0) and chains
//    prefetch retirement to cross-XCD atomic acks (~2k cy/tile, R7) or to
//    in-flight BW pacing (R8). Scheduling around it failed twice.
//  - Fix: DELETE the atomics. Each block owns GPB=50 consecutive graphs
//    (~1000 nodes, +/-3% imbalance); per-graph sums accumulate in a 25.6 KB
//    LDS array across the block's ~16 tiles; one coalesced flush at the end.
//    Loop VMEM = exactly 8 unconditional prefetch loads -> stage's vmcnt
//    wait is exact, with a full iteration (>=6k cy) of cover.
//  - Also removed: tile_seg kernel, hipMemsetAsync (flush fully writes every
//    owned row), per-tile starts reload (window lane-resident, loaded once).
//  - LDS 36.9 KB (Xs dbuf) + 25.6 KB (acc) = 62.5 KB <= 64 KB; 2 blocks/CU.
// Prediction: stage1 50-65 us, total ~340-360, LDS 62464, VGPR<=200 no spill.

typedef __bf16 bf16_t;
typedef bf16_t bf16x8 __attribute__((ext_vector_type(8)));
typedef float  f32x4  __attribute__((ext_vector_type(4)));

#define XS_STRIDE 144   // shorts; 288 B row = 72 dwords -> 4-way banks on b128
#define GPB 50          // graphs per block (50*128*4 B = 25.6 KB LDS accum)

__device__ __forceinline__ unsigned short f2bf(float f) {
  unsigned int u = __float_as_uint(f);
  u += 0x7fffu + ((u >> 16) & 1u);   // RNE
  return (unsigned short)(u >> 16);
}

// LDS-only barrier: drains this wave's LDS ops then barriers; global loads
// (vmcnt) stay in flight, so the pipelined next-tile loads overlap compute.
__device__ __forceinline__ void bar_lds() {
  asm volatile("s_waitcnt lgkmcnt(0)\n\ts_barrier" ::: "memory");
}

__global__ __launch_bounds__(256, 2)
void stage1_kernel(const float* __restrict__ X,
                   const float* __restrict__ Wu, const float* __restrict__ bu,
                   const float* __restrict__ Wg, const float* __restrict__ bg,
                   const int* __restrict__ starts,
                   float* __restrict__ gsum, int V, int G)
{
  __shared__ unsigned short Xs[2][64 * XS_STRIDE]; // double-buffered bf16 tile (36.9 KB)
  __shared__ float          acc[GPB * 128];        // block-private graph sums (25.6 KB)

  const int tid  = threadIdx.x;
  const int lane = tid & 63;
  const int wave = tid >> 6;          // 4 waves; wave owns f-strip [wave*32, +32)
  const int quad = lane >> 4;
  const int l15  = lane & 15;

  const int g_lo = blockIdx.x * GPB;
  const int ng   = min(GPB, G - g_lo);
  if (ng <= 0) return;                // block-uniform; never with exact grid

  // starts window for this block's graphs: loaded ONCE, lane-resident.
  // lane i holds starts[g_lo + i] (i <= ng <= 50 < 64).
  const int sv      = starts[min(g_lo + lane, G)];
  const int node_lo = __shfl(sv, 0);
  const int node_hi = __shfl(sv, ng);

  // Persistent B fragments (W_up / W_gate) in registers, loaded once per block.
  // B-frag layout: lane holds B[k = s*32 + quad*8 + j][n = lane&15].
  bf16x8 Bu[2][4], Bg[2][4];
  float bup[2], bgt[2];
#pragma unroll
  for (int t = 0; t < 2; ++t) {
    const int f = wave * 32 + t * 16 + l15;
    bup[t] = bu[f];
    bgt[t] = bg[f];
#pragma unroll
    for (int s = 0; s < 4; ++s) {
      const int k0 = s * 32 + quad * 8;
      union { unsigned short us[8]; bf16x8 v; } a, b;
#pragma unroll
      for (int j = 0; j < 8; ++j) {
        a.us[j] = f2bf(Wu[(k0 + j) * 128 + f]);
        b.us[j] = f2bf(Wg[(k0 + j) * 128 + f]);
      }
      Bu[t][s] = a.v;
      Bg[t][s] = b.v;
    }
  }

  // zero the accumulator (visible after the prologue barrier)
  for (int i = tid; i < GPB * 32; i += 256)
    *(f32x4*)&acc[i << 2] = f32x4{0.f, 0.f, 0.f, 0.f};

  const int ntl = (node_hi - node_lo + 63) >> 6;  // tiles for this block

  f32x4 ld[8];
  // preload tile 0 (clamped, unconditional; 64 nodes x 128 k as float4)
#pragma unroll
  for (int i = 0; i < 8; ++i) {
    const int flat = tid + i * 256;
    const int n = min(node_lo + (flat >> 5), V - 1);
    const int k = (flat & 31) << 2;
    ld[i] = *(const f32x4*)(X + (size_t)n * 128 + k);
  }

  int gi = 0;                         // local graph cursor across tiles
  for (int t = 0; t < ntl; ++t) {
    unsigned short* xb = Xs[t & 1];
    const int n0g   = node_lo + t * 64;
    const int n_end = min(n0g + 64, node_hi);

    // 1) stage regs -> LDS as packed bf16. The implicit vmcnt wait here is
    //    EXACT: the only outstanding VMEM is last iteration's 8 prefetch
    //    loads (no atomics anywhere in the loop), with a full iteration of
    //    cover behind them.
#pragma unroll
    for (int i = 0; i < 8; ++i) {
      const int flat = tid + i * 256;
      const int n = flat >> 5;
      const int k = (flat & 31) << 2;
      const unsigned int p0 =
          (unsigned int)f2bf(ld[i][0]) | ((unsigned int)f2bf(ld[i][1]) << 16);
      const unsigned int p1 =
          (unsigned int)f2bf(ld[i][2]) | ((unsigned int)f2bf(ld[i][3]) << 16);
      *(uint2*)&xb[n * XS_STRIDE + k] = make_uint2(p0, p1);
    }

    // 2) issue next tile's loads (clamped, unconditional)
    {
      const int m0 = node_lo + min(t + 1, ntl - 1) * 64;
#pragma unroll
      for (int i = 0; i < 8; ++i) {
        const int flat = tid + i * 256;
        const int n = min(m0 + (flat >> 5), V - 1);
        const int k = (flat & 31) << 2;
        ld[i] = *(const f32x4*)(X + (size_t)n * 128 + k);
      }
    }

    bar_lds();   // one barrier per tile: Xs[t&1] writes visible; prefetch in flight

    // 3) MFMA phase + in-register sigmoid epilogue: gv[sub][tt][r]
    float gv[4][2][4];
#pragma unroll
    for (int sub = 0; sub < 4; ++sub) {
      bf16x8 A[4];
      const int nl = sub * 16 + l15;   // A-frag: A[m=lane&15][k=quad*8+j]
#pragma unroll
      for (int s = 0; s < 4; ++s)
        A[s] = *(const bf16x8*)&xb[nl * XS_STRIDE + s * 32 + quad * 8];
#pragma unroll
      for (int tt = 0; tt < 2; ++tt) {
        f32x4 au = {0.f, 0.f, 0.f, 0.f};
        f32x4 ag = {0.f, 0.f, 0.f, 0.f};
#pragma unroll
        for (int s = 0; s < 4; ++s) {
          au = __builtin_amdgcn_mfma_f32_16x16x32_bf16(A[s], Bu[tt][s], au, 0, 0, 0);
          ag = __builtin_amdgcn_mfma_f32_16x16x32_bf16(A[s], Bg[tt][s], ag, 0, 0, 0);
        }
        // D layout: col=lane&15 (feature), row=quad*4+r (node within sub-16)
#pragma unroll
        for (int r = 0; r < 4; ++r) {
          const float up = au[r] + bup[tt];
          const float gt = ag[r] + bgt[tt];
          gv[sub][tt][r] = up * __builtin_amdgcn_rcpf(1.f + __expf(-gt));
        }
      }
    }

    // 4) segment reduction -> block-private LDS accumulator (NO atomics).
    //    Each wave handles its own 32-feature strip for every graph in the
    //    tile. Graph walk is wave-uniform via __shfl of the lane-resident
    //    starts window; cursor gi persists across tiles.
    {
      int i = gi;
      int sg = __shfl(sv, i);
      while (i < ng && sg < n_end) {
        const int snext = __shfl(sv, i + 1);
        const int r0 = max(sg, n0g) - n0g;
        const int r1 = min(snext - 1, n_end) - n0g;  // excludes graph's last node
        if (r1 > r0) {                                // wave-uniform branch
          float p0 = 0.f, p1 = 0.f;
#pragma unroll
          for (int sub = 0; sub < 4; ++sub) {
#pragma unroll
            for (int r = 0; r < 4; ++r) {
              const int row = sub * 16 + quad * 4 + r;
              const bool in = (row >= r0) && (row < r1);
              p0 += in ? gv[sub][0][r] : 0.f;
              p1 += in ? gv[sub][1][r] : 0.f;
            }
          }
          // butterfly across quads (lane^16, lane^32): all lanes get totals
          p0 += __shfl_xor(p0, 16); p0 += __shfl_xor(p0, 32);
          p1 += __shfl_xor(p1, 16); p1 += __shfl_xor(p1, 32);
          // bank-free RMW: quad0 -> banks 0-15, quad1 -> banks 16-31;
          // each (graph,f) cell touched by exactly one lane block-wide
          if (quad == 0)
            acc[i * 128 + wave * 32 + l15] += p0;
          else if (quad == 1)
            acc[i * 128 + wave * 32 + 16 + l15] += p1;
        }
        if (snext > n_end) break;   // graph continues into next tile
        sg = snext;
        ++i;
      }
      gi = i;
    }
    // no end-of-loop barrier: next iteration's bar_lds fences buffer reuse
  }

  // flush: block-private sums -> global (plain coalesced stores; every owned
  // row fully written, so no d_out memset is needed anywhere)
  __syncthreads();
  for (int i = tid; i < ng * 32; i += 256) {
    const int row = i >> 5;
    const int c   = (i & 31) << 2;
    *(f32x4*)(gsum + (size_t)(g_lo + row) * 128 + c) = *(const f32x4*)&acc[row * 128 + c];
  }
}

__global__ __launch_bounds__(256)
void stage2_kernel(const float* __restrict__ Wf, const float* __restrict__ bfv,
                   float* __restrict__ out, int G)
{
  __shared__ float Gsm[32 * 132];
  const int g0  = blockIdx.x * 32;
  const int tid = threadIdx.x;

  // stage this block's 32 graph_sums rows (then safe to overwrite in-place)
  for (int i = tid; i < 32 * 32; i += 256) {
    const int r = i >> 5;
    const int c = (i & 31) << 2;
    const int g = g0 + r;
    f32x4 v = {0.f, 0.f, 0.f, 0.f};
    if (g < G) v = *(const f32x4*)(out + (size_t)g * 128 + c);
    *(f32x4*)&Gsm[r * 132 + c] = v;
  }
  __syncthreads();

  const int fq  = tid & 31;
  const int f0  = fq << 2;            // 4 consecutive features
  const int grp = tid >> 5;           // 8 groups x 4 graphs
  float acc2[4][4];
#pragma unroll
  for (int i = 0; i < 4; ++i)
#pragma unroll
    for (int j = 0; j < 4; ++j) acc2[i][j] = 0.f;

#pragma unroll 4
  for (int k = 0; k < 128; ++k) {
    const f32x4 w = *(const f32x4*)(Wf + (size_t)k * 128 + f0);
#pragma unroll
    for (int i = 0; i < 4; ++i) {
      const float gv = Gsm[(grp * 4 + i) * 132 + k];
      acc2[i][0] += gv * w[0];
      acc2[i][1] += gv * w[1];
      acc2[i][2] += gv * w[2];
      acc2[i][3] += gv * w[3];
    }
  }

  const f32x4 bb = *(const f32x4*)(bfv + f0);
#pragma unroll
  for (int i = 0; i < 4; ++i) {
    const int g = g0 + grp * 4 + i;
    if (g < G) {
      f32x4 o = {acc2[i][0] + bb[0], acc2[i][1] + bb[1],
                 acc2[i][2] + bb[2], acc2[i][3] + bb[3]};
      *(f32x4*)(out + (size_t)g * 128 + f0) = o;
    }
  }
}

extern "C" void kernel_launch(void* const* d_in, const int* in_sizes, int n_in,
                              void* d_out, int out_size, void* d_ws, size_t ws_size,
                              hipStream_t stream)
{
  const float* X      = (const float*)d_in[0];
  const float* Wu     = (const float*)d_in[1];
  const float* bu     = (const float*)d_in[2];
  const float* Wg     = (const float*)d_in[3];
  const float* bg     = (const float*)d_in[4];
  const float* Wf     = (const float*)d_in[5];
  const float* bf_    = (const float*)d_in[6];
  const int*   starts = (const int*)d_in[7];

  const int G = in_sizes[7] - 1;
  const int V = in_sizes[0] / 128;

  float* gsum = (float*)d_out;           // graph_sums accumulates in d_out
  const int nb1 = (G + GPB - 1) / GPB;   // one block per GPB graphs

  stage1_kernel<<<nb1, 256, 0, stream>>>(X, Wu, bu, Wg, bg, starts, gsum, V, G);
  stage2_kernel<<<(G + 31) / 32, 256, 0, stream>>>(Wf, bf_, gsum, G);
}